// Round 4
// baseline (134.597 us; speedup 1.0000x reference)
//
#include <hip/hip_runtime.h>
#include <hip/hip_bf16.h>
#include <math.h>
#include <string.h>

#define BB   16
#define NN   128
#define NCC  32
#define HH   256
#define AA   64
#define DEGN 3
#define BNR  (BB*NN)   // 2048 rows

typedef __bf16 bf16x8 __attribute__((ext_vector_type(8)));
typedef float  f32x4  __attribute__((ext_vector_type(4)));

// ---------------------------------------------------------------------------
// Kernel 1: masked mean-pool of condition vectors -> pooled [B,H]
// ---------------------------------------------------------------------------
__global__ __launch_bounds__(256) void k_pool(const float* __restrict__ cond,
                                              const float* __restrict__ cmask,
                                              float* __restrict__ pooled) {
    int b = blockIdx.x, h = threadIdx.x;
    float s = 0.f, ms = 0.f;
    for (int c = 0; c < NCC; ++c) {
        float mk = cmask[b * NCC + c];
        s  += cond[(b * NCC + c) * HH + h] * mk;
        ms += mk;
    }
    pooled[b * HH + h] = s / fmaxf(ms, 1.0f);
}

// ---------------------------------------------------------------------------
// Kernel 2: dv[d,b,:] = pooled[b,:] @ Wc[d]  (also writes dvs output)
// ---------------------------------------------------------------------------
__global__ __launch_bounds__(256) void k_dv(const float* __restrict__ pooled,
                                            const float* __restrict__ Wc,
                                            float* __restrict__ dv,
                                            float* __restrict__ dv_out) {
    int d = blockIdx.x / BB, b = blockIdx.x % BB, h = threadIdx.x;
    const float* Wd = Wc + (size_t)d * HH * HH;
    const float* pb = pooled + b * HH;
    float acc = 0.f;
    for (int k = 0; k < HH; ++k) acc += pb[k] * Wd[k * HH + h];
    int idx = (d * BB + b) * HH + h;
    dv[idx]     = acc;
    dv_out[idx] = acc;
}

// ---------------------------------------------------------------------------
// Kernel 3: hbuf[d,row,:] = gelu_tanh(x[row,:] @ W1[d] + b1[d] + dv[d,b])
// ---------------------------------------------------------------------------
__global__ __launch_bounds__(256) void k_enc(const float* __restrict__ x,
                                             const float* __restrict__ W1,
                                             const float* __restrict__ b1,
                                             const float* __restrict__ dv,
                                             float* __restrict__ hbuf) {
    const int RT = BNR / 16;  // 128 row-tiles
    int d = blockIdx.x / RT, rt = blockIdx.x % RT;
    int row0 = rt * 16;
    int h = threadIdx.x;
    __shared__ float xs[16][HH];
    #pragma unroll
    for (int rr = 0; rr < 16; ++rr) xs[rr][h] = x[(row0 + rr) * HH + h];
    __syncthreads();

    float acc[16];
    #pragma unroll
    for (int r = 0; r < 16; ++r) acc[r] = 0.f;

    const float* Wd = W1 + (size_t)d * HH * HH;
    for (int k = 0; k < HH; k += 4) {
        float w0 = Wd[(k + 0) * HH + h], w1 = Wd[(k + 1) * HH + h];
        float w2 = Wd[(k + 2) * HH + h], w3 = Wd[(k + 3) * HH + h];
        #pragma unroll
        for (int r = 0; r < 16; ++r) {
            float4 xv = *(const float4*)&xs[r][k];
            acc[r] += xv.x * w0 + xv.y * w1 + xv.z * w2 + xv.w * w3;
        }
    }
    int b = row0 / NN;
    float add = b1[d * HH + h] + dv[(d * BB + b) * HH + h];
    #pragma unroll
    for (int r = 0; r < 16; ++r) {
        float v = acc[r] + add;
        float u = 0.7978845608028654f * (v + 0.044715f * v * v * v);
        float g = 0.5f * v * (1.0f + tanhf(u));
        hbuf[((size_t)d * BNR + row0 + r) * HH + h] = g;
    }
}

// ---------------------------------------------------------------------------
// Kernel 4: yv[d,row,:] = (hbuf[d,row,:] @ Wlin[d] + blin[d]) * x_mask[row]
// ---------------------------------------------------------------------------
__global__ __launch_bounds__(256) void k_lin(const float* __restrict__ hbuf,
                                             const float* __restrict__ Wlin,
                                             const float* __restrict__ blin,
                                             const float* __restrict__ xmask,
                                             float* __restrict__ yv) {
    const int RT = BNR / 16;
    int d = blockIdx.x / RT, rt = blockIdx.x % RT;
    int row0 = rt * 16;
    int t = threadIdx.x;
    int a = t & 63, rg = t >> 6;
    __shared__ float hs[16][HH];
    for (int e = t; e < 16 * HH; e += 256) {
        int rr = e >> 8, k = e & 255;
        hs[rr][k] = hbuf[((size_t)d * BNR + row0 + rr) * HH + k];
    }
    __syncthreads();

    const float* Wd = Wlin + (size_t)d * HH * AA;
    float acc[4] = {0.f, 0.f, 0.f, 0.f};
    for (int k = 0; k < HH; k += 4) {
        float w0 = Wd[(k + 0) * AA + a], w1 = Wd[(k + 1) * AA + a];
        float w2 = Wd[(k + 2) * AA + a], w3 = Wd[(k + 3) * AA + a];
        #pragma unroll
        for (int rr = 0; rr < 4; ++rr) {
            float4 hv = *(const float4*)&hs[rg * 4 + rr][k];
            acc[rr] += hv.x * w0 + hv.y * w1 + hv.z * w2 + hv.w * w3;
        }
    }
    float bl = blin[d * AA + a];
    #pragma unroll
    for (int rr = 0; rr < 4; ++rr) {
        int row = row0 + rg * 4 + rr;
        yv[((size_t)d * BNR + row) * AA + a] = (acc[rr] + bl) * xmask[row];
    }
}

// ---------------------------------------------------------------------------
// Kernel 5: symmetric contraction via bf16 MFMA, transpose-free, x-batched.
// For each (b, x):  out*4096 = A'B'^T + B'A'^T  with
//   A'[r][k<64]  = s0[k]*Y1[r,k] + s1[k]*Y0[r,k];  A'[r][64+i] = s2[i]*Y0[r,i]
//   B'[r][k<64]  = Y2[r,k];                         B'[r][64+i] = Y1[r,i]
// B' is x-INDEPENDENT: each block owns 4 consecutive x of one b, stages B'
// once, then per x restages only A'. 512 blocks x 64KB LDS = 2 blocks/CU,
// all co-resident (single scheduling round).
// ---------------------------------------------------------------------------
__device__ __forceinline__ unsigned int pk2(float lo, float hi) {
    __hip_bfloat162 h2 = __float22bfloat162_rn(make_float2(lo, hi));
    unsigned int u;
    memcpy(&u, &h2, 4);
    return u;
}

__global__ __launch_bounds__(256, 2) void k_contract(const float* __restrict__ yv,
                                                     float* __restrict__ outp) {
    __shared__ __align__(16) char lds[65536];  // A': [0,32K), B': [32K,64K)
    char* Albs = lds;
    char* Blbs = lds + 32768;

    const int t  = threadIdx.x;
    const int b  = blockIdx.x >> 5;       // 32 x-groups per batch
    const int xg = blockIdx.x & 31;

    const float* y0p = yv + (size_t)(0 * BNR + b * NN) * AA;
    const float* y1p = yv + (size_t)(1 * BNR + b * NN) * AA;
    const float* y2p = yv + (size_t)(2 * BNR + b * NN) * AA;

    const int lane = t & 63;
    const int wid  = t >> 6;
    const int li   = lane & 31;           // column-pair index
    const int rh   = lane >> 5;           // row parity within wave's row-pair

    // ---- stage B' once (x-independent): each wave stages 32 rows ----
    #pragma unroll
    for (int it = 0; it < 16; ++it) {
        const int r   = wid * 32 + it * 2 + rh;
        const int swz = (r & 7) << 4;
        const float2 v1 = *(const float2*)&y1p[r * AA + 2 * li];
        const float2 v2 = *(const float2*)&y2p[r * AA + 2 * li];
        *(unsigned int*)(Blbs + r * 256 + ((  4 * li      ) ^ swz)) = pk2(v2.x, v2.y);
        *(unsigned int*)(Blbs + r * 256 + ((128 + 4 * li  ) ^ swz)) = pk2(v1.x, v1.y);
    }

    const int wy = (wid >> 1) * 64, wz = (wid & 1) * 64;
    const int rl = lane & 15, hi = lane >> 4;
    const float inv = 1.0f / 4096.0f;

    for (int xi = 0; xi < 4; ++xi) {
        const int xr = xg * 4 + xi;
        // per-lane s values, then broadcast pairs for this lane's columns
        const float s0 = y0p[xr * AA + lane];
        const float s1 = y1p[xr * AA + lane];
        const float s2 = y2p[xr * AA + lane];
        const float s0a = __shfl(s0, 2 * li), s0b = __shfl(s0, 2 * li + 1);
        const float s1a = __shfl(s1, 2 * li), s1b = __shfl(s1, 2 * li + 1);
        const float s2a = __shfl(s2, 2 * li), s2b = __shfl(s2, 2 * li + 1);

        // ---- stage A'(x): each wave stages 32 rows ----
        #pragma unroll
        for (int it = 0; it < 16; ++it) {
            const int r   = wid * 32 + it * 2 + rh;
            const int swz = (r & 7) << 4;
            const float2 v0 = *(const float2*)&y0p[r * AA + 2 * li];
            const float2 v1 = *(const float2*)&y1p[r * AA + 2 * li];
            unsigned int a1 = pk2(s0a * v1.x + s1a * v0.x, s0b * v1.y + s1b * v0.y);
            unsigned int a2 = pk2(s2a * v0.x, s2b * v0.y);
            *(unsigned int*)(Albs + r * 256 + ((  4 * li      ) ^ swz)) = a1;
            *(unsigned int*)(Albs + r * 256 + ((128 + 4 * li  ) ^ swz)) = a2;
        }
        __syncthreads();   // A' (and B' on xi=0) visible to all waves

        // ---- MFMA: wave computes 64x64 sub-tile; U=[A'|B'], V=[B'|A'] ----
        f32x4 acc[4][4];
        #pragma unroll
        for (int mi = 0; mi < 4; ++mi)
            #pragma unroll
            for (int ni = 0; ni < 4; ++ni) {
                f32x4 z = {0.f, 0.f, 0.f, 0.f};
                acc[mi][ni] = z;
            }

        #pragma unroll
        for (int half = 0; half < 2; ++half) {
            const char* Ua = half ? Blbs : Albs;
            const char* Vb = half ? Albs : Blbs;
            #pragma unroll
            for (int ks = 0; ks < 4; ++ks) {
                bf16x8 af[4], bf[4];
                #pragma unroll
                for (int mi = 0; mi < 4; ++mi) {
                    int row = wy + mi * 16 + rl;
                    af[mi] = *(const bf16x8*)(Ua + row * 256 +
                              ((ks * 64 + hi * 16) ^ ((row & 7) << 4)));
                }
                #pragma unroll
                for (int ni = 0; ni < 4; ++ni) {
                    int row = wz + ni * 16 + rl;
                    bf[ni] = *(const bf16x8*)(Vb + row * 256 +
                              ((ks * 64 + hi * 16) ^ ((row & 7) << 4)));
                }
                #pragma unroll
                for (int mi = 0; mi < 4; ++mi)
                    #pragma unroll
                    for (int ni = 0; ni < 4; ++ni)
                        acc[mi][ni] = __builtin_amdgcn_mfma_f32_16x16x32_bf16(
                            af[mi], bf[ni], acc[mi][ni], 0, 0, 0);
            }
        }

        // ---- epilogue (C/D layout: col=lane&15, row=hi*4+j) ----
        float* osl = outp + ((size_t)(b * NN + xr)) * (NN * NN);
        #pragma unroll
        for (int mi = 0; mi < 4; ++mi) {
            #pragma unroll
            for (int ni = 0; ni < 4; ++ni) {
                int col   = wz + ni * 16 + rl;
                int rbase = wy + mi * 16 + hi * 4;
                #pragma unroll
                for (int j = 0; j < 4; ++j)
                    osl[(rbase + j) * NN + col] = acc[mi][ni][j] * inv;
            }
        }
        __syncthreads();   // protect A' before next x overwrites it
    }
}

// ---------------------------------------------------------------------------
extern "C" void kernel_launch(void* const* d_in, const int* in_sizes, int n_in,
                              void* d_out, int out_size, void* d_ws, size_t ws_size,
                              hipStream_t stream) {
    const float* x     = (const float*)d_in[0];
    const float* xmask = (const float*)d_in[1];
    const float* cond  = (const float*)d_in[2];
    const float* cmask = (const float*)d_in[3];
    const float* W1    = (const float*)d_in[4];
    const float* b1    = (const float*)d_in[5];
    const float* Wc    = (const float*)d_in[6];
    const float* Wlin  = (const float*)d_in[7];
    const float* blin  = (const float*)d_in[8];

    float* out = (float*)d_out;
    float* ws  = (float*)d_ws;

    float* pooled = ws;                        // 16*256
    float* dv     = ws + 4096;                 // 3*16*256
    float* hbuf   = ws + 16384;                // 3*2048*256
    float* yv     = ws + 16384 + 1572864;      // 3*2048*64
    float* dv_out = out + (size_t)BB * NN * NN * NN;

    k_pool    <<<dim3(BB),              dim3(256), 0, stream>>>(cond, cmask, pooled);
    k_dv      <<<dim3(DEGN * BB),       dim3(256), 0, stream>>>(pooled, Wc, dv, dv_out);
    k_enc     <<<dim3(DEGN * (BNR/16)), dim3(256), 0, stream>>>(x, W1, b1, dv, hbuf);
    k_lin     <<<dim3(DEGN * (BNR/16)), dim3(256), 0, stream>>>(hbuf, Wlin, blin, xmask, yv);
    k_contract<<<dim3(BB * NN / 4),     dim3(256), 0, stream>>>(yv, out);
}